// Round 12
// baseline (1420.272 us; speedup 1.0000x reference)
//
#include <hip/hip_runtime.h>

#define B_   32
#define T_   512
#define D_   256
#define C_   64
#define R_   4
#define RD_  64
#define OUT_ 256

// ---------------------------------------------------------------------------
__device__ __forceinline__ void bar_lds() {
  asm volatile("s_waitcnt lgkmcnt(0)" ::: "memory");
  __builtin_amdgcn_s_barrier();
  asm volatile("" ::: "memory");
}

// ---- DPP-based wave reductions (VALU pipe) ---------------------------------
template <int CTRL>
__device__ __forceinline__ float dpp_add(float v) {
  int s = __builtin_amdgcn_update_dpp(0, __float_as_int(v), CTRL, 0xF, 0xF, true);
  return v + __int_as_float(s);
}
__device__ __forceinline__ float row16_sum(float v) {
  v = dpp_add<0xB1>(v);   // quad_perm [1,0,3,2]
  v = dpp_add<0x4E>(v);   // quad_perm [2,3,0,1]
  v = dpp_add<0x141>(v);  // row_half_mirror
  v = dpp_add<0x140>(v);  // row_mirror
  return v;
}
__device__ __forceinline__ float rlane(float v, int l) {
  return __int_as_float(__builtin_amdgcn_readlane(__float_as_int(v), l));
}
__device__ __forceinline__ int rlane_i(int v, int l) {
  return __builtin_amdgcn_readlane(v, l);
}
__device__ __forceinline__ float wave_sum_dpp(float v) {
  const float r = row16_sum(v);
  return (rlane(r, 0) + rlane(r, 16)) + (rlane(r, 32) + rlane(r, 48));
}

// ---------------------------------------------------------------------------
// Xpre = X @ W   (16384 x 256) @ (256 x 256), f32
__global__ __launch_bounds__(256) void xpre_kernel(const float* __restrict__ X,
                                                   const float* __restrict__ W,
                                                   float* __restrict__ XP) {
  __shared__ __align__(16) float xs[32][D_];
  const int j = threadIdx.x;
  const int row0 = blockIdx.x * 32;
  for (int k = 0; k < 32; ++k)
    xs[k][j] = X[(size_t)(row0 + k) * D_ + j];
  __syncthreads();
  float acc[32];
#pragma unroll
  for (int k = 0; k < 32; ++k) acc[k] = 0.f;
  for (int d4 = 0; d4 < D_ / 4; ++d4) {
    const float w0 = W[(d4 * 4 + 0) * OUT_ + j];
    const float w1 = W[(d4 * 4 + 1) * OUT_ + j];
    const float w2 = W[(d4 * 4 + 2) * OUT_ + j];
    const float w3 = W[(d4 * 4 + 3) * OUT_ + j];
#pragma unroll
    for (int k = 0; k < 32; ++k) {
      const float4 x4 = *(const float4*)&xs[k][d4 * 4];
      acc[k] = fmaf(x4.x, w0, fmaf(x4.y, w1, fmaf(x4.z, w2, fmaf(x4.w, w3, acc[k]))));
    }
  }
  for (int k = 0; k < 32; ++k)
    XP[(size_t)(row0 + k) * OUT_ + j] = acc[k];
}

// ---------------------------------------------------------------------------
// attnK: attention weights + aggs for ALL (b,t). One wave per (b,t).
// walG[bt*256 + r*64 + c] = (ri[c]==r ? alpha[c] : 0).
__global__ __launch_bounds__(256) void attnK(const float* __restrict__ X,
                                             const int* __restrict__ Ri,
                                             const int* __restrict__ Ei,
                                             const float* __restrict__ Watt,
                                             float* __restrict__ walG,
                                             float* __restrict__ aggs) {
  const int wv = threadIdx.x >> 6;
  const int lane = threadIdx.x & 63;
  const size_t bt = (size_t)blockIdx.x * 4 + wv;
  const int r4 = lane >> 4, seg = lane & 15;

  float y = 0.f;
#pragma unroll
  for (int q = 0; q < 4; ++q) {
    const float4 wt = *(const float4*)&Watt[(r4 << 8) + (seg << 4) + (q << 2)];
    const float4 xv = *(const float4*)&X[bt * D_ + (seg << 4) + (q << 2)];
    y = fmaf(xv.x, wt.x, y);
    y = fmaf(xv.y, wt.y, y);
    y = fmaf(xv.z, wt.z, y);
    y = fmaf(xv.w, wt.w, y);
  }
  y = row16_sum(y);
  const float y0 = rlane(y, 0), y1 = rlane(y, 16);
  const float y2 = rlane(y, 32), y3 = rlane(y, 48);
  const int ric = Ri[bt * C_ + lane];
  const float eic = (float)Ei[bt * C_ + lane];
  float yv = (ric & 1) ? y1 : y0;
  const float yw = (ric & 1) ? y3 : y2;
  yv = (ric & 2) ? yw : yv;
  const float am = __expf(yv) * eic;  // EPS=1e-100 underflows in f32
  const float tot = wave_sum_dpp(am);
  const float alpha = __fdividef(am, tot);

  const float w0 = (ric == 0) ? alpha : 0.f;
  const float w1 = (ric == 1) ? alpha : 0.f;
  const float w2 = (ric == 2) ? alpha : 0.f;
  const float w3 = (ric == 3) ? alpha : 0.f;
  walG[bt * 256 + 0 * C_ + lane] = w0;
  walG[bt * 256 + 1 * C_ + lane] = w1;
  walG[bt * 256 + 2 * C_ + lane] = w2;
  walG[bt * 256 + 3 * C_ + lane] = w3;
  const float s0 = wave_sum_dpp(w0);
  const float s1 = wave_sum_dpp(w1);
  const float s2 = wave_sum_dpp(w2);
  const float s3 = wave_sum_dpp(w3);
  if (lane == 0) {
    float4 v = {s0, s1, s2, s3};
    *(float4*)&aggs[bt * R_] = v;
  }
}

// ---------------------------------------------------------------------------
// gruA: DUAL-chain recurrent core. 16 blocks x 256 threads (4 waves, 1/SIMD).
// Each block runs batches 2*bid and 2*bid+1 interleaved: U registers are
// SHARED between the chains, and the two independent instruction streams
// fill each other's latency bubbles (1 wave/SIMD has no TLP otherwise).
// Branch-free main body: tlists zero-padded to kMax; commits masked by k<nT.
// Per chain, per step (same validated structure as round 11):
//  A : prev partials from mtreg (wal via readlane) -> shp
//  B1: prevX; K-split h2h partials (64 RL, 1:4 RL:FMA) -> pBred
//  B2: reduce; gates; hnew (masked store); reload parity set for k+2
//  C : mtreg select-update (ro/eo packed, via readlane; commit-masked)
__global__ __launch_bounds__(256, 1) void gruA(
    const int* __restrict__ M, const int* __restrict__ Eo,
    const int* __restrict__ Ro, const float* __restrict__ U,
    const float* __restrict__ Bv, const float* __restrict__ XP,
    const float* __restrict__ walG, float* __restrict__ hbuf) {
  __shared__ __align__(16) float shp[2][4][256];    // [chain][aw][r*64+d]
  __shared__ __align__(16) float pBred[2][4][256];  // [chain][kw][j]
  __shared__ __align__(16) float sh_hnew[2][OUT_];
  __shared__ int sh_tl[2][T_];
  __shared__ int sh_nT[2];

  const int tid = threadIdx.x;
  const int lane = tid & 63;
  const int w = tid >> 6;
  const size_t bt0A = (size_t)(blockIdx.x * 2) * T_;
  const size_t bt0B = bt0A + T_;

  // U slice (shared by both chains): ureg[jj*64+i] = U[64w+i][jj*64+lane]
  float ureg[256];
#pragma unroll
  for (int jj = 0; jj < 4; ++jj)
#pragma unroll
    for (int i = 0; i < 64; ++i)
      ureg[(jj << 6) + i] = U[(size_t)((w << 6) + i) * OUT_ + (jj << 6) + lane];
  const float breg = Bv[tid];

  // m state per chain: mt*[q] = mt[16w+q][lane]
  float mtA[16], mtB[16];
#pragma unroll
  for (int q = 0; q < 16; ++q) { mtA[q] = 0.f; mtB[q] = 0.f; }

  // zero-pad tlists, then scatter m=1 step indices (wave 0 -> A, wave 1 -> B)
  for (int i = tid; i < 2 * T_; i += 256) ((int*)sh_tl)[i] = 0;
  __syncthreads();
  if (w < 2) {
    const size_t base0 = (w == 0) ? bt0A : bt0B;
    int base = 0;
    for (int ch = 0; ch < 8; ++ch) {
      const int mv = M[base0 + (ch << 6) + lane];
      const unsigned long long mask = __ballot(mv != 0);
      if (mv) {
        const unsigned long long lt = ((lane == 63) ? ~0ull : ((1ull << (lane + 1)) - 1)) >> 1;
        sh_tl[w][base + __popcll(mask & lt)] = (ch << 6) + lane;
      }
      base += __popcll(mask);
    }
    if (lane == 0) sh_nT[w] = base;
  }
  __syncthreads();
  const int nTA = sh_nT[0], nTB = sh_nT[1];
  const int kMax = (nTA > nTB) ? nTA : nTB;
  if (kMax == 0) return;

  // parity register sets per chain:
  //  wal: wal[r=tid&3][c = 16w + (lane>>2)]  (A: readlane at 4q+r)
  //  xp : XP[., tid]
  //  re : Ro | (Eo<<8) at c = 16w + (lane&15) (C: readlane at q)
  const int cwal = (w << 4) + (lane >> 2);
  const int croeo = (w << 4) + (lane & 15);
  float walA0, xpA0, walA1, xpA1, walB0, xpB0, walB1, xpB1;
  int reA0, reA1, reB0, reB1;
  {
    const int tA = sh_tl[0][0], tB = sh_tl[1][0];
    walA0 = walG[(bt0A + tA) * 256 + ((tid & 3) << 6) + cwal];
    xpA0 = XP[(bt0A + tA) * 256 + tid];
    reA0 = Ro[(bt0A + tA) * C_ + croeo] | (Eo[(bt0A + tA) * C_ + croeo] << 8);
    walB0 = walG[(bt0B + tB) * 256 + ((tid & 3) << 6) + cwal];
    xpB0 = XP[(bt0B + tB) * 256 + tid];
    reB0 = Ro[(bt0B + tB) * C_ + croeo] | (Eo[(bt0B + tB) * C_ + croeo] << 8);
  }
  {
    const int tA = sh_tl[0][1], tB = sh_tl[1][1];  // padded 0 if nT<2
    walA1 = walG[(bt0A + tA) * 256 + ((tid & 3) << 6) + cwal];
    xpA1 = XP[(bt0A + tA) * 256 + tid];
    reA1 = Ro[(bt0A + tA) * C_ + croeo] | (Eo[(bt0A + tA) * C_ + croeo] << 8);
    walB1 = walG[(bt0B + tB) * 256 + ((tid & 3) << 6) + cwal];
    xpB1 = XP[(bt0B + tB) * 256 + tid];
    reB1 = Ro[(bt0B + tB) * C_ + croeo] | (Eo[(bt0B + tB) * C_ + croeo] << 8);
  }

  auto do_step = [&](int k, float& walA, float& xpA, int& reA,
                     float& walB, float& xpB, int& reB) {
    const int tA = sh_tl[0][k], tB = sh_tl[1][k];
    const bool cmA = (k < nTA), cmB = (k < nTB);
    const int reAc = reA, reBc = reB;  // consume before B2 reload

    // ---- A: prev partials from mt regs (both chains, interleaved) ----
    float aA0 = 0.f, aA1 = 0.f, aA2 = 0.f, aA3 = 0.f;
    float aB0 = 0.f, aB1 = 0.f, aB2 = 0.f, aB3 = 0.f;
#pragma unroll
    for (int q = 0; q < 16; ++q) {
      const float mA = mtA[q], mB = mtB[q];
      aA0 = fmaf(rlane(walA, 4 * q + 0), mA, aA0);
      aA1 = fmaf(rlane(walA, 4 * q + 1), mA, aA1);
      aA2 = fmaf(rlane(walA, 4 * q + 2), mA, aA2);
      aA3 = fmaf(rlane(walA, 4 * q + 3), mA, aA3);
      aB0 = fmaf(rlane(walB, 4 * q + 0), mB, aB0);
      aB1 = fmaf(rlane(walB, 4 * q + 1), mB, aB1);
      aB2 = fmaf(rlane(walB, 4 * q + 2), mB, aB2);
      aB3 = fmaf(rlane(walB, 4 * q + 3), mB, aB3);
    }
    shp[0][w][0 * 64 + lane] = aA0;
    shp[0][w][1 * 64 + lane] = aA1;
    shp[0][w][2 * 64 + lane] = aA2;
    shp[0][w][3 * 64 + lane] = aA3;
    shp[1][w][0 * 64 + lane] = aB0;
    shp[1][w][1 * 64 + lane] = aB1;
    shp[1][w][2 * 64 + lane] = aB2;
    shp[1][w][3 * 64 + lane] = aB3;
    bar_lds();

    // ---- B1: prevX both; K-split h2h partials both (1:8 RL:FMA mix) ----
    const float pXA = ((shp[0][0][tid] + shp[0][1][tid]) +
                       (shp[0][2][tid] + shp[0][3][tid]));  // prev[64w+lane]
    const float pXB = ((shp[1][0][tid] + shp[1][1][tid]) +
                       (shp[1][2][tid] + shp[1][3][tid]));
    float pA0 = 0.f, pA1 = 0.f, pA2 = 0.f, pA3 = 0.f;
    float pB0 = 0.f, pB1 = 0.f, pB2 = 0.f, pB3 = 0.f;
#pragma unroll
    for (int i = 0; i < 64; ++i) {
      const float kA = rlane(pXA, i);
      const float kB = rlane(pXB, i);
      const float u0 = ureg[i], u1 = ureg[64 + i];
      const float u2 = ureg[128 + i], u3 = ureg[192 + i];
      pA0 = fmaf(kA, u0, pA0);
      pA1 = fmaf(kA, u1, pA1);
      pA2 = fmaf(kA, u2, pA2);
      pA3 = fmaf(kA, u3, pA3);
      pB0 = fmaf(kB, u0, pB0);
      pB1 = fmaf(kB, u1, pB1);
      pB2 = fmaf(kB, u2, pB2);
      pB3 = fmaf(kB, u3, pB3);
    }
    pBred[0][w][0 * 64 + lane] = pA0;
    pBred[0][w][1 * 64 + lane] = pA1;
    pBred[0][w][2 * 64 + lane] = pA2;
    pBred[0][w][3 * 64 + lane] = pA3;
    pBred[1][w][0 * 64 + lane] = pB0;
    pBred[1][w][1 * 64 + lane] = pB1;
    pBred[1][w][2 * 64 + lane] = pB2;
    pBred[1][w][3 * 64 + lane] = pB3;
    bar_lds();

    // ---- B2: reduce; gates; hnew; masked hbuf; reload parity for k+2 ----
    const float h2hA = ((pBred[0][0][tid] + pBred[0][1][tid]) +
                        (pBred[0][2][tid] + pBred[0][3][tid]));
    const float h2hB = ((pBred[1][0][tid] + pBred[1][1][tid]) +
                        (pBred[1][2][tid] + pBred[1][3][tid]));
    const float g1A = xpA + h2hA + breg;
    const float g1B = xpB + h2hB + breg;
    const float rgA = 1.f / (1.f + __expf(-g1A));
    const float rgB = 1.f / (1.f + __expf(-g1B));
    const float tgA = xpA + rgA * h2hA + breg;
    const float tgB = xpB + rgB * h2hB + breg;
    const float e2A = __expf(2.f * tgA);
    const float e2B = __expf(2.f * tgB);
    const float htA = 1.f - 2.f / (e2A + 1.f);  // tanh
    const float htB = 1.f - 2.f / (e2B + 1.f);
    const float hnA = (1.f - rgA) * pXA + rgA * htA;
    const float hnB = (1.f - rgB) * pXB + rgB * htB;
    sh_hnew[0][tid] = hnA;
    sh_hnew[1][tid] = hnB;
    if (cmA) hbuf[(bt0A + tA) * OUT_ + tid] = hnA;
    if (cmB) hbuf[(bt0B + tB) * OUT_ + tid] = hnB;
    {
      const int kk = (k + 2 < T_) ? k + 2 : T_ - 1;
      const int tA2 = sh_tl[0][kk], tB2 = sh_tl[1][kk];
      walA = walG[(bt0A + tA2) * 256 + ((tid & 3) << 6) + cwal];
      xpA = XP[(bt0A + tA2) * 256 + tid];
      reA = Ro[(bt0A + tA2) * C_ + croeo] | (Eo[(bt0A + tA2) * C_ + croeo] << 8);
      walB = walG[(bt0B + tB2) * 256 + ((tid & 3) << 6) + cwal];
      xpB = XP[(bt0B + tB2) * 256 + tid];
      reB = Ro[(bt0B + tB2) * C_ + croeo] | (Eo[(bt0B + tB2) * C_ + croeo] << 8);
    }
    bar_lds();

    // ---- C: mt select-update, commit-masked (both chains) ----
    const float hA0 = sh_hnew[0][0 * 64 + lane];
    const float hA1 = sh_hnew[0][1 * 64 + lane];
    const float hA2 = sh_hnew[0][2 * 64 + lane];
    const float hA3 = sh_hnew[0][3 * 64 + lane];
    const float hB0 = sh_hnew[1][0 * 64 + lane];
    const float hB1 = sh_hnew[1][1 * 64 + lane];
    const float hB2 = sh_hnew[1][2 * 64 + lane];
    const float hB3 = sh_hnew[1][3 * 64 + lane];
#pragma unroll
    for (int q = 0; q < 16; ++q) {
      const int ra = rlane_i(reAc, q);   // uniform: ro | eo<<8
      const int rb = rlane_i(reBc, q);
      const float haA = (ra & 1) ? hA1 : hA0;
      const float hbA = (ra & 1) ? hA3 : hA2;
      const float hsA = (ra & 2) ? hbA : haA;
      mtA[q] = (cmA && (ra & 0x100)) ? hsA : mtA[q];
      const float haB = (rb & 1) ? hB1 : hB0;
      const float hbB = (rb & 1) ? hB3 : hB2;
      const float hsB = (rb & 2) ? hbB : haB;
      mtB[q] = (cmB && (rb & 0x100)) ? hsB : mtB[q];
    }
    // no barrier: next A writes only shp (last read pre-bar2); sh_hnew next
    // written in B2(k+1), two barriers away.
  };

  for (int k = 0; k < kMax; k += 2) {
    do_step(k, walA0, xpA0, reA0, walB0, xpB0, reB0);
    if (k + 1 < kMax)
      do_step(k + 1, walA1, xpA1, reA1, walB1, xpB1, reB1);
  }
}

// ---------------------------------------------------------------------------
// memsB: mems[b,t,c,:] = hbuf(tau)[ro(tau,c)*64+:], tau = last step<=t with
// M&Eo, else 0. One block per (b,c).
__global__ __launch_bounds__(512) void memsB(const int* __restrict__ M,
                                             const int* __restrict__ Eo,
                                             const int* __restrict__ Ro,
                                             const float* __restrict__ hbuf,
                                             float* __restrict__ mems) {
  __shared__ int lastA[T_];
  const int tid = threadIdx.x;
  const int b = blockIdx.x >> 6;
  const int c = blockIdx.x & 63;
  const size_t bt0 = (size_t)b * T_;
  {
    const int upd = M[bt0 + tid] & Eo[(bt0 + tid) * C_ + c];
    lastA[tid] = upd ? tid : -1;
  }
  __syncthreads();
  for (int off = 1; off < T_; off <<= 1) {
    const int u = (tid >= off) ? lastA[tid - off] : -1;
    const int v = lastA[tid];
    __syncthreads();
    lastA[tid] = (u > v) ? u : v;
    __syncthreads();
  }
  const int d = tid & 63;
  const int t8 = tid >> 6;
  for (int tt = 0; tt < 64; ++tt) {
    const int t = (tt << 3) + t8;
    const int tau = lastA[t];
    float v = 0.f;
    if (tau >= 0) {
      const int rc = Ro[(bt0 + tau) * C_ + c];
      v = hbuf[(bt0 + tau) * OUT_ + (rc << 6) + d];
    }
    mems[((bt0 + t) * C_ + c) * RD_ + d] = v;
  }
}

// ---------------------------------------------------------------------------
// outsC: outs[b,t,:] = hbuf(tauM), tauM = last M=1 step <= t, else 0.
// In place on hbuf/outs, descending t.
__global__ __launch_bounds__(512) void outsC(const int* __restrict__ M,
                                             float* __restrict__ outs) {
  __shared__ int lastM[T_];
  const int tid = threadIdx.x;
  const int b = blockIdx.x;
  const size_t bt0 = (size_t)b * T_;
  lastM[tid] = M[bt0 + tid] ? tid : -1;
  __syncthreads();
  for (int off = 1; off < T_; off <<= 1) {
    const int u = (tid >= off) ? lastM[tid - off] : -1;
    const int v = lastM[tid];
    __syncthreads();
    lastM[tid] = (u > v) ? u : v;
    __syncthreads();
  }
  const int j = tid & 255;
  const int th = tid >> 8;
  for (int k = 0; k < 256; ++k) {
    const int t = 511 - (k << 1) - th;
    const int tau = lastM[t];
    const float v = (tau >= 0) ? outs[(bt0 + tau) * OUT_ + j] : 0.f;
    __syncthreads();
    outs[(bt0 + t) * OUT_ + j] = v;
  }
}

// ---------------------------------------------------------------------------
extern "C" void kernel_launch(void* const* d_in, const int* in_sizes, int n_in,
                              void* d_out, int out_size, void* d_ws, size_t ws_size,
                              hipStream_t stream) {
  const float* X = (const float*)d_in[0];
  const int* M = (const int*)d_in[1];
  const int* Ei = (const int*)d_in[2];
  const int* Eo = (const int*)d_in[3];
  const int* Ri = (const int*)d_in[4];
  const int* Ro = (const int*)d_in[5];
  const float* W = (const float*)d_in[6];
  const float* U = (const float*)d_in[7];
  const float* Bv = (const float*)d_in[8];
  const float* Watt = (const float*)d_in[9];

  float* outs = (float*)d_out;
  float* mems = outs + (size_t)B_ * T_ * OUT_;
  float* aggs = mems + (size_t)B_ * T_ * C_ * RD_;
  float* XP = (float*)d_ws;   // 16.8 MB scratch
  float* hbuf = outs;         // hnew history aliases outs (outsC finalizes)
  float* walG = mems;         // alpha scratch aliases mems (memsB overwrites)

  xpre_kernel<<<dim3(B_ * T_ / 32), dim3(256), 0, stream>>>(X, W, XP);
  attnK<<<dim3(B_ * T_ / 4), dim3(256), 0, stream>>>(X, Ri, Ei, Watt, walG, aggs);
  gruA<<<dim3(B_ / 2), dim3(256), 0, stream>>>(M, Eo, Ro, U, Bv, XP, walG, hbuf);
  memsB<<<dim3(B_ * C_), dim3(512), 0, stream>>>(M, Eo, Ro, hbuf, mems);
  outsC<<<dim3(B_), dim3(512), 0, stream>>>(M, outs);
}

// Round 13
// 775.098 us; speedup vs baseline: 1.8324x; 1.8324x over previous
//
#include <hip/hip_runtime.h>

#define B_   32
#define T_   512
#define D_   256
#define C_   64
#define R_   4
#define RD_  64
#define OUT_ 256

// ---------------------------------------------------------------------------
__device__ __forceinline__ void bar_lds() {
  asm volatile("s_waitcnt lgkmcnt(0)" ::: "memory");
  __builtin_amdgcn_s_barrier();
  asm volatile("" ::: "memory");
}

// ---- DPP-based wave reductions (VALU pipe) ---------------------------------
template <int CTRL>
__device__ __forceinline__ float dpp_add(float v) {
  int s = __builtin_amdgcn_update_dpp(0, __float_as_int(v), CTRL, 0xF, 0xF, true);
  return v + __int_as_float(s);
}
__device__ __forceinline__ float row16_sum(float v) {
  v = dpp_add<0xB1>(v);   // quad_perm [1,0,3,2]
  v = dpp_add<0x4E>(v);   // quad_perm [2,3,0,1]
  v = dpp_add<0x141>(v);  // row_half_mirror
  v = dpp_add<0x140>(v);  // row_mirror
  return v;
}
__device__ __forceinline__ float rlane(float v, int l) {
  return __int_as_float(__builtin_amdgcn_readlane(__float_as_int(v), l));
}
__device__ __forceinline__ int rlane_i(int v, int l) {
  return __builtin_amdgcn_readlane(v, l);
}
__device__ __forceinline__ float wave_sum_dpp(float v) {
  const float r = row16_sum(v);
  return (rlane(r, 0) + rlane(r, 16)) + (rlane(r, 32) + rlane(r, 48));
}

// ---------------------------------------------------------------------------
// Xpre = X @ W   (16384 x 256) @ (256 x 256), f32
__global__ __launch_bounds__(256) void xpre_kernel(const float* __restrict__ X,
                                                   const float* __restrict__ W,
                                                   float* __restrict__ XP) {
  __shared__ __align__(16) float xs[32][D_];
  const int j = threadIdx.x;
  const int row0 = blockIdx.x * 32;
  for (int k = 0; k < 32; ++k)
    xs[k][j] = X[(size_t)(row0 + k) * D_ + j];
  __syncthreads();
  float acc[32];
#pragma unroll
  for (int k = 0; k < 32; ++k) acc[k] = 0.f;
  for (int d4 = 0; d4 < D_ / 4; ++d4) {
    const float w0 = W[(d4 * 4 + 0) * OUT_ + j];
    const float w1 = W[(d4 * 4 + 1) * OUT_ + j];
    const float w2 = W[(d4 * 4 + 2) * OUT_ + j];
    const float w3 = W[(d4 * 4 + 3) * OUT_ + j];
#pragma unroll
    for (int k = 0; k < 32; ++k) {
      const float4 x4 = *(const float4*)&xs[k][d4 * 4];
      acc[k] = fmaf(x4.x, w0, fmaf(x4.y, w1, fmaf(x4.z, w2, fmaf(x4.w, w3, acc[k]))));
    }
  }
  for (int k = 0; k < 32; ++k)
    XP[(size_t)(row0 + k) * OUT_ + j] = acc[k];
}

// ---------------------------------------------------------------------------
// attnK: attention weights + aggs for ALL (b,t). One wave per (b,t).
// walG[bt*256 + r*64 + c] = (ri[c]==r ? alpha[c] : 0).
__global__ __launch_bounds__(256) void attnK(const float* __restrict__ X,
                                             const int* __restrict__ Ri,
                                             const int* __restrict__ Ei,
                                             const float* __restrict__ Watt,
                                             float* __restrict__ walG,
                                             float* __restrict__ aggs) {
  const int wv = threadIdx.x >> 6;
  const int lane = threadIdx.x & 63;
  const size_t bt = (size_t)blockIdx.x * 4 + wv;
  const int r4 = lane >> 4, seg = lane & 15;

  float y = 0.f;
#pragma unroll
  for (int q = 0; q < 4; ++q) {
    const float4 wt = *(const float4*)&Watt[(r4 << 8) + (seg << 4) + (q << 2)];
    const float4 xv = *(const float4*)&X[bt * D_ + (seg << 4) + (q << 2)];
    y = fmaf(xv.x, wt.x, y);
    y = fmaf(xv.y, wt.y, y);
    y = fmaf(xv.z, wt.z, y);
    y = fmaf(xv.w, wt.w, y);
  }
  y = row16_sum(y);
  const float y0 = rlane(y, 0), y1 = rlane(y, 16);
  const float y2 = rlane(y, 32), y3 = rlane(y, 48);
  const int ric = Ri[bt * C_ + lane];
  const float eic = (float)Ei[bt * C_ + lane];
  float yv = (ric & 1) ? y1 : y0;
  const float yw = (ric & 1) ? y3 : y2;
  yv = (ric & 2) ? yw : yv;
  const float am = __expf(yv) * eic;  // EPS=1e-100 underflows in f32
  const float tot = wave_sum_dpp(am);
  const float alpha = __fdividef(am, tot);

  const float w0 = (ric == 0) ? alpha : 0.f;
  const float w1 = (ric == 1) ? alpha : 0.f;
  const float w2 = (ric == 2) ? alpha : 0.f;
  const float w3 = (ric == 3) ? alpha : 0.f;
  walG[bt * 256 + 0 * C_ + lane] = w0;
  walG[bt * 256 + 1 * C_ + lane] = w1;
  walG[bt * 256 + 2 * C_ + lane] = w2;
  walG[bt * 256 + 3 * C_ + lane] = w3;
  const float s0 = wave_sum_dpp(w0);
  const float s1 = wave_sum_dpp(w1);
  const float s2 = wave_sum_dpp(w2);
  const float s3 = wave_sum_dpp(w3);
  if (lane == 0) {
    float4 v = {s0, s1, s2, s3};
    *(float4*)&aggs[bt * R_] = v;
  }
}

// ---------------------------------------------------------------------------
// gruA: recurrent core. 32 blocks x 512 threads (8 waves, 2 waves/SIMD).
// Same validated phase structure as round 11, but split across 8 waves so
// each SIMD hosts 2 waves — TLP fills the per-wave latency bubbles (LDS
// loads, RL->FMA hazards) that round 12 proved ILP cannot.
//  A : wave w owns c in [8w,8w+8): mtreg[8]; 32 RL -> shp[w][r*64+d]
//  B1: prevX at kidx=32w+(lane&31) (8 b32 sums); K-split h2h over K-range
//      [32w,32w+32): 32 RL : 128 FMA with ureg[128]; shprev[j] stash
//  B2: (waves 0-3) h2h = 8-way pBred sum; gates; hnew; all: reload k+2
//  C : mtreg select-update for its 8 c's (ro/eo packed, via readlane)
__global__ __launch_bounds__(512, 2) void gruA(
    const int* __restrict__ M, const int* __restrict__ Eo,
    const int* __restrict__ Ro, const float* __restrict__ U,
    const float* __restrict__ Bv, const float* __restrict__ XP,
    const float* __restrict__ walG, float* __restrict__ hbuf) {
  __shared__ __align__(16) float shp[8][256];    // [wave][r*64+d] prev partials
  __shared__ __align__(16) float pBred[8][256];  // [wave][j] h2h partials
  __shared__ __align__(16) float shprev[OUT_];   // prev[j]
  __shared__ __align__(16) float sh_hnew[OUT_];
  __shared__ int sh_tl[T_];
  __shared__ int sh_nT;

  const int tid = threadIdx.x;
  const int lane = tid & 63;
  const int w = tid >> 6;      // 0..7
  const int b = blockIdx.x;
  const size_t bt0 = (size_t)b * T_;

  // U slice: ureg[jj*32+i] = U[32w+i][jj*64+lane]  (K-range 32 per wave)
  float ureg[128];
#pragma unroll
  for (int jj = 0; jj < 4; ++jj)
#pragma unroll
    for (int i = 0; i < 32; ++i)
      ureg[(jj << 5) + i] = U[(size_t)((w << 5) + i) * OUT_ + (jj << 6) + lane];
  const float breg = Bv[tid & 255];  // used by waves 0-3

  // m state: mtreg[q] = mt[8w+q][lane], init 0
  float mtreg[8];
#pragma unroll
  for (int q = 0; q < 8; ++q) mtreg[q] = 0.f;

  // tlist: indices of m=1 steps (wave 0, ballot prefix scan)
  if (tid < 64) {
    int base = 0;
    for (int ch = 0; ch < 8; ++ch) {
      const int mv = M[bt0 + (ch << 6) + lane];
      const unsigned long long mask = __ballot(mv != 0);
      if (mv) {
        const unsigned long long lt = ((lane == 63) ? ~0ull : ((1ull << (lane + 1)) - 1)) >> 1;
        sh_tl[base + __popcll(mask & lt)] = (ch << 6) + lane;
      }
      base += __popcll(mask);
    }
    if (lane == 0) sh_nT = base;
  }
  __syncthreads();
  const int nT = sh_nT;
  if (nT == 0) return;

  // parity register sets:
  //  walS : wal[r = lane&3][c = 8w + (lane>>3)]   (A: readlane at 8q+r)
  //  xpS  : XP[., tid]  (waves 0-3 only)
  //  reS  : Ro | (Eo<<8) at c = 8w + (lane&7)     (C: readlane at q)
  const int cwal = (w << 3) + (lane >> 3);
  const int rwal = lane & 3;
  const int croeo = (w << 3) + (lane & 7);
  float walS0 = 0.f, xpS0 = 0.f, walS1 = 0.f, xpS1 = 0.f;
  int reS0 = 0, reS1 = 0;
  {
    const int t0 = sh_tl[0];
    walS0 = walG[(bt0 + t0) * 256 + (rwal << 6) + cwal];
    if (w < 4) xpS0 = XP[(bt0 + t0) * 256 + tid];
    reS0 = Ro[(bt0 + t0) * C_ + croeo] | (Eo[(bt0 + t0) * C_ + croeo] << 8);
  }
  if (nT > 1) {
    const int t1 = sh_tl[1];
    walS1 = walG[(bt0 + t1) * 256 + (rwal << 6) + cwal];
    if (w < 4) xpS1 = XP[(bt0 + t1) * 256 + tid];
    reS1 = Ro[(bt0 + t1) * C_ + croeo] | (Eo[(bt0 + t1) * C_ + croeo] << 8);
  }

  auto do_step = [&](int k, float& walS, float& xpS, int& reS) {
    const size_t bt = bt0 + sh_tl[k];
    const int reC = reS;  // consume before the k+2 reload overwrites

    // ---- A: prev partials from mtreg (pure VALU, 32 RL) -> shp ----
    float a0 = 0.f, a1 = 0.f, a2 = 0.f, a3 = 0.f;
#pragma unroll
    for (int q = 0; q < 8; ++q) {
      const float mq = mtreg[q];
      a0 = fmaf(rlane(walS, 8 * q + 0), mq, a0);
      a1 = fmaf(rlane(walS, 8 * q + 1), mq, a1);
      a2 = fmaf(rlane(walS, 8 * q + 2), mq, a2);
      a3 = fmaf(rlane(walS, 8 * q + 3), mq, a3);
    }
    shp[w][0 * 64 + lane] = a0;
    shp[w][1 * 64 + lane] = a1;
    shp[w][2 * 64 + lane] = a2;
    shp[w][3 * 64 + lane] = a3;
    bar_lds();

    // ---- B1: prevX at kidx; K-split h2h partials (32 RL : 128 FMA) ----
    const int kidx = (w << 5) + (lane & 31);
    const float px = ((shp[0][kidx] + shp[1][kidx]) + (shp[2][kidx] + shp[3][kidx])) +
                     ((shp[4][kidx] + shp[5][kidx]) + (shp[6][kidx] + shp[7][kidx]));
    if (lane < 32) shprev[kidx] = px;
    float p0 = 0.f, p1 = 0.f, p2 = 0.f, p3 = 0.f;
#pragma unroll
    for (int i = 0; i < 32; ++i) {
      const float pk = rlane(px, i);  // prev[32w + i], wave-uniform
      p0 = fmaf(pk, ureg[i], p0);
      p1 = fmaf(pk, ureg[32 + i], p1);
      p2 = fmaf(pk, ureg[64 + i], p2);
      p3 = fmaf(pk, ureg[96 + i], p3);
    }
    pBred[w][0 * 64 + lane] = p0;
    pBred[w][1 * 64 + lane] = p1;
    pBred[w][2 * 64 + lane] = p2;
    pBred[w][3 * 64 + lane] = p3;
    bar_lds();

    // ---- B2: gates on waves 0-3; reload parity set for t_{k+2} (all) ----
    if (w < 4) {
      const float h2h = ((pBred[0][tid] + pBred[1][tid]) +
                         (pBred[2][tid] + pBred[3][tid])) +
                        ((pBred[4][tid] + pBred[5][tid]) +
                         (pBred[6][tid] + pBred[7][tid]));
      const float pOwn = shprev[tid];
      const float g1 = xpS + h2h + breg;
      const float rg = 1.f / (1.f + __expf(-g1));
      const float targ = xpS + rg * h2h + breg;
      const float e2 = __expf(2.f * targ);
      const float ht = 1.f - 2.f / (e2 + 1.f);  // tanh
      const float hn = (1.f - rg) * pOwn + rg * ht;
      sh_hnew[tid] = hn;
      hbuf[bt * OUT_ + tid] = hn;
    }
    if (k + 2 < nT) {
      const int t2 = sh_tl[k + 2];
      walS = walG[(bt0 + t2) * 256 + (rwal << 6) + cwal];
      if (w < 4) xpS = XP[(bt0 + t2) * 256 + tid];
      reS = Ro[(bt0 + t2) * C_ + croeo] | (Eo[(bt0 + t2) * C_ + croeo] << 8);
    }
    bar_lds();

    // ---- C: mtreg select-update (8 RL; hnew via 4 conflict-free b32) ----
    const float h0 = sh_hnew[0 * 64 + lane];
    const float h1 = sh_hnew[1 * 64 + lane];
    const float h2 = sh_hnew[2 * 64 + lane];
    const float h3 = sh_hnew[3 * 64 + lane];
#pragma unroll
    for (int q = 0; q < 8; ++q) {
      const int re = rlane_i(reC, q);   // uniform: ro | eo<<8
      const int ro = re & 0xFF;
      const float ha = (ro & 1) ? h1 : h0;
      const float hb = (ro & 1) ? h3 : h2;
      const float hs = (ro & 2) ? hb : ha;
      mtreg[q] = (re & 0x100) ? hs : mtreg[q];
    }
    // no barrier: next A writes only shp (its B1 readers are 2 bars back);
    // sh_hnew is next written in B2(k+1), two barriers away.
  };

  for (int k = 0; k < nT; k += 2) {
    do_step(k, walS0, xpS0, reS0);
    if (k + 1 < nT) do_step(k + 1, walS1, xpS1, reS1);
  }
}

// ---------------------------------------------------------------------------
// memsB: mems[b,t,c,:] = hbuf(tau)[ro(tau,c)*64+:], tau = last step<=t with
// M&Eo, else 0. One block per (b,c).
__global__ __launch_bounds__(512) void memsB(const int* __restrict__ M,
                                             const int* __restrict__ Eo,
                                             const int* __restrict__ Ro,
                                             const float* __restrict__ hbuf,
                                             float* __restrict__ mems) {
  __shared__ int lastA[T_];
  const int tid = threadIdx.x;
  const int b = blockIdx.x >> 6;
  const int c = blockIdx.x & 63;
  const size_t bt0 = (size_t)b * T_;
  {
    const int upd = M[bt0 + tid] & Eo[(bt0 + tid) * C_ + c];
    lastA[tid] = upd ? tid : -1;
  }
  __syncthreads();
  for (int off = 1; off < T_; off <<= 1) {
    const int u = (tid >= off) ? lastA[tid - off] : -1;
    const int v = lastA[tid];
    __syncthreads();
    lastA[tid] = (u > v) ? u : v;
    __syncthreads();
  }
  const int d = tid & 63;
  const int t8 = tid >> 6;
  for (int tt = 0; tt < 64; ++tt) {
    const int t = (tt << 3) + t8;
    const int tau = lastA[t];
    float v = 0.f;
    if (tau >= 0) {
      const int rc = Ro[(bt0 + tau) * C_ + c];
      v = hbuf[(bt0 + tau) * OUT_ + (rc << 6) + d];
    }
    mems[((bt0 + t) * C_ + c) * RD_ + d] = v;
  }
}

// ---------------------------------------------------------------------------
// outsC: outs[b,t,:] = hbuf(tauM), tauM = last M=1 step <= t, else 0.
// In place on hbuf/outs, descending t.
__global__ __launch_bounds__(512) void outsC(const int* __restrict__ M,
                                             float* __restrict__ outs) {
  __shared__ int lastM[T_];
  const int tid = threadIdx.x;
  const int b = blockIdx.x;
  const size_t bt0 = (size_t)b * T_;
  lastM[tid] = M[bt0 + tid] ? tid : -1;
  __syncthreads();
  for (int off = 1; off < T_; off <<= 1) {
    const int u = (tid >= off) ? lastM[tid - off] : -1;
    const int v = lastM[tid];
    __syncthreads();
    lastM[tid] = (u > v) ? u : v;
    __syncthreads();
  }
  const int j = tid & 255;
  const int th = tid >> 8;
  for (int k = 0; k < 256; ++k) {
    const int t = 511 - (k << 1) - th;
    const int tau = lastM[t];
    const float v = (tau >= 0) ? outs[(bt0 + tau) * OUT_ + j] : 0.f;
    __syncthreads();
    outs[(bt0 + t) * OUT_ + j] = v;
  }
}

// ---------------------------------------------------------------------------
extern "C" void kernel_launch(void* const* d_in, const int* in_sizes, int n_in,
                              void* d_out, int out_size, void* d_ws, size_t ws_size,
                              hipStream_t stream) {
  const float* X = (const float*)d_in[0];
  const int* M = (const int*)d_in[1];
  const int* Ei = (const int*)d_in[2];
  const int* Eo = (const int*)d_in[3];
  const int* Ri = (const int*)d_in[4];
  const int* Ro = (const int*)d_in[5];
  const float* W = (const float*)d_in[6];
  const float* U = (const float*)d_in[7];
  const float* Bv = (const float*)d_in[8];
  const float* Watt = (const float*)d_in[9];

  float* outs = (float*)d_out;
  float* mems = outs + (size_t)B_ * T_ * OUT_;
  float* aggs = mems + (size_t)B_ * T_ * C_ * RD_;
  float* XP = (float*)d_ws;   // 16.8 MB scratch
  float* hbuf = outs;         // hnew history aliases outs (outsC finalizes)
  float* walG = mems;         // alpha scratch aliases mems (memsB overwrites)

  xpre_kernel<<<dim3(B_ * T_ / 32), dim3(256), 0, stream>>>(X, W, XP);
  attnK<<<dim3(B_ * T_ / 4), dim3(256), 0, stream>>>(X, Ri, Ei, Watt, walG, aggs);
  gruA<<<dim3(B_), dim3(512), 0, stream>>>(M, Eo, Ro, U, Bv, XP, walG, hbuf);
  memsB<<<dim3(B_ * C_), dim3(512), 0, stream>>>(M, Eo, Ro, hbuf, mems);
  outsC<<<dim3(B_), dim3(512), 0, stream>>>(M, outs);
}

// Round 14
// 767.899 us; speedup vs baseline: 1.8496x; 1.0094x over previous
//
#include <hip/hip_runtime.h>

#define B_   32
#define T_   512
#define D_   256
#define C_   64
#define R_   4
#define RD_  64
#define OUT_ 256

// ---------------------------------------------------------------------------
__device__ __forceinline__ void bar_lds() {
  asm volatile("s_waitcnt lgkmcnt(0)" ::: "memory");
  __builtin_amdgcn_s_barrier();
  asm volatile("" ::: "memory");
}

// ---- DPP-based wave reductions (VALU pipe) ---------------------------------
template <int CTRL>
__device__ __forceinline__ float dpp_add(float v) {
  int s = __builtin_amdgcn_update_dpp(0, __float_as_int(v), CTRL, 0xF, 0xF, true);
  return v + __int_as_float(s);
}
__device__ __forceinline__ float row16_sum(float v) {
  v = dpp_add<0xB1>(v);   // quad_perm [1,0,3,2]
  v = dpp_add<0x4E>(v);   // quad_perm [2,3,0,1]
  v = dpp_add<0x141>(v);  // row_half_mirror
  v = dpp_add<0x140>(v);  // row_mirror
  return v;
}
__device__ __forceinline__ float rlane(float v, int l) {
  return __int_as_float(__builtin_amdgcn_readlane(__float_as_int(v), l));
}
__device__ __forceinline__ int rlane_i(int v, int l) {
  return __builtin_amdgcn_readlane(v, l);
}
__device__ __forceinline__ float wave_sum_dpp(float v) {
  const float r = row16_sum(v);
  return (rlane(r, 0) + rlane(r, 16)) + (rlane(r, 32) + rlane(r, 48));
}

// ---------------------------------------------------------------------------
// Xpre = X @ W   (16384 x 256) @ (256 x 256), f32
__global__ __launch_bounds__(256) void xpre_kernel(const float* __restrict__ X,
                                                   const float* __restrict__ W,
                                                   float* __restrict__ XP) {
  __shared__ __align__(16) float xs[32][D_];
  const int j = threadIdx.x;
  const int row0 = blockIdx.x * 32;
  for (int k = 0; k < 32; ++k)
    xs[k][j] = X[(size_t)(row0 + k) * D_ + j];
  __syncthreads();
  float acc[32];
#pragma unroll
  for (int k = 0; k < 32; ++k) acc[k] = 0.f;
  for (int d4 = 0; d4 < D_ / 4; ++d4) {
    const float w0 = W[(d4 * 4 + 0) * OUT_ + j];
    const float w1 = W[(d4 * 4 + 1) * OUT_ + j];
    const float w2 = W[(d4 * 4 + 2) * OUT_ + j];
    const float w3 = W[(d4 * 4 + 3) * OUT_ + j];
#pragma unroll
    for (int k = 0; k < 32; ++k) {
      const float4 x4 = *(const float4*)&xs[k][d4 * 4];
      acc[k] = fmaf(x4.x, w0, fmaf(x4.y, w1, fmaf(x4.z, w2, fmaf(x4.w, w3, acc[k]))));
    }
  }
  for (int k = 0; k < 32; ++k)
    XP[(size_t)(row0 + k) * OUT_ + j] = acc[k];
}

// ---------------------------------------------------------------------------
// attnK: attention weights + aggs for ALL (b,t). One wave per (b,t).
// walG[bt*256 + r*64 + c] = (ri[c]==r ? alpha[c] : 0).
__global__ __launch_bounds__(256) void attnK(const float* __restrict__ X,
                                             const int* __restrict__ Ri,
                                             const int* __restrict__ Ei,
                                             const float* __restrict__ Watt,
                                             float* __restrict__ walG,
                                             float* __restrict__ aggs) {
  const int wv = threadIdx.x >> 6;
  const int lane = threadIdx.x & 63;
  const size_t bt = (size_t)blockIdx.x * 4 + wv;
  const int r4 = lane >> 4, seg = lane & 15;

  float y = 0.f;
#pragma unroll
  for (int q = 0; q < 4; ++q) {
    const float4 wt = *(const float4*)&Watt[(r4 << 8) + (seg << 4) + (q << 2)];
    const float4 xv = *(const float4*)&X[bt * D_ + (seg << 4) + (q << 2)];
    y = fmaf(xv.x, wt.x, y);
    y = fmaf(xv.y, wt.y, y);
    y = fmaf(xv.z, wt.z, y);
    y = fmaf(xv.w, wt.w, y);
  }
  y = row16_sum(y);
  const float y0 = rlane(y, 0), y1 = rlane(y, 16);
  const float y2 = rlane(y, 32), y3 = rlane(y, 48);
  const int ric = Ri[bt * C_ + lane];
  const float eic = (float)Ei[bt * C_ + lane];
  float yv = (ric & 1) ? y1 : y0;
  const float yw = (ric & 1) ? y3 : y2;
  yv = (ric & 2) ? yw : yv;
  const float am = __expf(yv) * eic;  // EPS=1e-100 underflows in f32
  const float tot = wave_sum_dpp(am);
  const float alpha = __fdividef(am, tot);

  const float w0 = (ric == 0) ? alpha : 0.f;
  const float w1 = (ric == 1) ? alpha : 0.f;
  const float w2 = (ric == 2) ? alpha : 0.f;
  const float w3 = (ric == 3) ? alpha : 0.f;
  walG[bt * 256 + 0 * C_ + lane] = w0;
  walG[bt * 256 + 1 * C_ + lane] = w1;
  walG[bt * 256 + 2 * C_ + lane] = w2;
  walG[bt * 256 + 3 * C_ + lane] = w3;
  const float s0 = wave_sum_dpp(w0);
  const float s1 = wave_sum_dpp(w1);
  const float s2 = wave_sum_dpp(w2);
  const float s3 = wave_sum_dpp(w3);
  if (lane == 0) {
    float4 v = {s0, s1, s2, s3};
    *(float4*)&aggs[bt * R_] = v;
  }
}

// ---------------------------------------------------------------------------
// gruA: recurrent core. 32 blocks x 1024 threads (16 waves, 4 waves/SIMD).
// Round-13 structure, split twice as fine: more TLP per SIMD to fill the
// per-wave latency bubbles (round 13 proved 1->2 waves/SIMD helps).
//  A : wave w owns c in [4w,4w+4): mtreg[4]; 16 RL + 16 FMA -> shp[w][r*64+d]
//  B1: prevX at kidx=16w+(lane&15) (16 bcast reads); h2h over K-range
//      [16w,16w+16): 16 RL : 64 FMA with ureg[64]; shprev stash
//  B2: (waves 0-3) h2h = 16-way pBred sum; gates; hnew; all: reload k+2
//  C : mtreg select-update for its 4 c's (ro/eo packed, via readlane)
__global__ __launch_bounds__(1024, 4) void gruA(
    const int* __restrict__ M, const int* __restrict__ Eo,
    const int* __restrict__ Ro, const float* __restrict__ U,
    const float* __restrict__ Bv, const float* __restrict__ XP,
    const float* __restrict__ walG, float* __restrict__ hbuf) {
  __shared__ __align__(16) float shp[16][256];    // [wave][r*64+d] prev partials
  __shared__ __align__(16) float pBred[16][256];  // [wave][j] h2h partials
  __shared__ __align__(16) float shprev[OUT_];    // prev[j]
  __shared__ __align__(16) float sh_hnew[OUT_];
  __shared__ int sh_tl[T_];
  __shared__ int sh_nT;

  const int tid = threadIdx.x;
  const int lane = tid & 63;
  const int w = tid >> 6;      // 0..15
  const int b = blockIdx.x;
  const size_t bt0 = (size_t)b * T_;

  // U slice: ureg[jj*16+i] = U[16w+i][jj*64+lane]  (K-range 16 per wave)
  float ureg[64];
#pragma unroll
  for (int jj = 0; jj < 4; ++jj)
#pragma unroll
    for (int i = 0; i < 16; ++i)
      ureg[(jj << 4) + i] = U[(size_t)((w << 4) + i) * OUT_ + (jj << 6) + lane];
  const float breg = Bv[tid & 255];  // used by waves 0-3

  // m state: mtreg[q] = mt[4w+q][lane], init 0
  float mtreg[4];
#pragma unroll
  for (int q = 0; q < 4; ++q) mtreg[q] = 0.f;

  // tlist: indices of m=1 steps (wave 0, ballot prefix scan)
  if (tid < 64) {
    int base = 0;
    for (int ch = 0; ch < 8; ++ch) {
      const int mv = M[bt0 + (ch << 6) + lane];
      const unsigned long long mask = __ballot(mv != 0);
      if (mv) {
        const unsigned long long lt = ((lane == 63) ? ~0ull : ((1ull << (lane + 1)) - 1)) >> 1;
        sh_tl[base + __popcll(mask & lt)] = (ch << 6) + lane;
      }
      base += __popcll(mask);
    }
    if (lane == 0) sh_nT = base;
  }
  __syncthreads();
  const int nT = sh_nT;
  if (nT == 0) return;

  // parity register sets:
  //  walS : wal[r = lane&3][c = 4w + (lane>>4)]   (A: readlane at (q<<4)+r)
  //  xpS  : XP[., tid]  (waves 0-3 only)
  //  reS  : Ro | (Eo<<8) at c = 4w + (lane&3)     (C: readlane at q)
  const int cwal = (w << 2) + (lane >> 4);
  const int rwal = lane & 3;
  const int croeo = (w << 2) + (lane & 3);
  float walS0 = 0.f, xpS0 = 0.f, walS1 = 0.f, xpS1 = 0.f;
  int reS0 = 0, reS1 = 0;
  {
    const int t0 = sh_tl[0];
    walS0 = walG[(bt0 + t0) * 256 + (rwal << 6) + cwal];
    if (w < 4) xpS0 = XP[(bt0 + t0) * 256 + tid];
    reS0 = Ro[(bt0 + t0) * C_ + croeo] | (Eo[(bt0 + t0) * C_ + croeo] << 8);
  }
  if (nT > 1) {
    const int t1 = sh_tl[1];
    walS1 = walG[(bt0 + t1) * 256 + (rwal << 6) + cwal];
    if (w < 4) xpS1 = XP[(bt0 + t1) * 256 + tid];
    reS1 = Ro[(bt0 + t1) * C_ + croeo] | (Eo[(bt0 + t1) * C_ + croeo] << 8);
  }

  auto do_step = [&](int k, float& walS, float& xpS, int& reS) {
    const size_t bt = bt0 + sh_tl[k];
    const int reC = reS;  // consume before the k+2 reload overwrites

    // ---- A: prev partials from mtreg (16 RL + 16 FMA) -> shp ----
    float a0 = 0.f, a1 = 0.f, a2 = 0.f, a3 = 0.f;
#pragma unroll
    for (int q = 0; q < 4; ++q) {
      const float mq = mtreg[q];
      a0 = fmaf(rlane(walS, (q << 4) + 0), mq, a0);
      a1 = fmaf(rlane(walS, (q << 4) + 1), mq, a1);
      a2 = fmaf(rlane(walS, (q << 4) + 2), mq, a2);
      a3 = fmaf(rlane(walS, (q << 4) + 3), mq, a3);
    }
    shp[w][0 * 64 + lane] = a0;
    shp[w][1 * 64 + lane] = a1;
    shp[w][2 * 64 + lane] = a2;
    shp[w][3 * 64 + lane] = a3;
    bar_lds();

    // ---- B1: prevX at kidx (16 bcast reads); h2h partials (16 RL:64 FMA) ----
    const int kidx = (w << 4) + (lane & 15);
    float px = 0.f;
#pragma unroll
    for (int sw = 0; sw < 16; sw += 4) {
      const float t0 = shp[sw + 0][kidx], t1 = shp[sw + 1][kidx];
      const float t2 = shp[sw + 2][kidx], t3 = shp[sw + 3][kidx];
      px += (t0 + t1) + (t2 + t3);
    }
    if (lane < 16) shprev[kidx] = px;
    float p0 = 0.f, p1 = 0.f, p2 = 0.f, p3 = 0.f;
#pragma unroll
    for (int i = 0; i < 16; ++i) {
      const float pk = rlane(px, i);  // prev[16w + i], wave-uniform
      p0 = fmaf(pk, ureg[i], p0);
      p1 = fmaf(pk, ureg[16 + i], p1);
      p2 = fmaf(pk, ureg[32 + i], p2);
      p3 = fmaf(pk, ureg[48 + i], p3);
    }
    pBred[w][0 * 64 + lane] = p0;
    pBred[w][1 * 64 + lane] = p1;
    pBred[w][2 * 64 + lane] = p2;
    pBred[w][3 * 64 + lane] = p3;
    bar_lds();

    // ---- B2: gates on waves 0-3; reload parity set for t_{k+2} (all) ----
    if (w < 4) {
      float h2h = 0.f;
#pragma unroll
      for (int kw = 0; kw < 16; kw += 4) {
        const float t0 = pBred[kw + 0][tid], t1 = pBred[kw + 1][tid];
        const float t2 = pBred[kw + 2][tid], t3 = pBred[kw + 3][tid];
        h2h += (t0 + t1) + (t2 + t3);
      }
      const float pOwn = shprev[tid];
      const float g1 = xpS + h2h + breg;
      const float rg = 1.f / (1.f + __expf(-g1));
      const float targ = xpS + rg * h2h + breg;
      const float e2 = __expf(2.f * targ);
      const float ht = 1.f - 2.f / (e2 + 1.f);  // tanh
      const float hn = (1.f - rg) * pOwn + rg * ht;
      sh_hnew[tid] = hn;
      hbuf[bt * OUT_ + tid] = hn;
    }
    if (k + 2 < nT) {
      const int t2 = sh_tl[k + 2];
      walS = walG[(bt0 + t2) * 256 + (rwal << 6) + cwal];
      if (w < 4) xpS = XP[(bt0 + t2) * 256 + tid];
      reS = Ro[(bt0 + t2) * C_ + croeo] | (Eo[(bt0 + t2) * C_ + croeo] << 8);
    }
    bar_lds();

    // ---- C: mtreg select-update (4 RL; hnew via 4 conflict-free b32) ----
    const float h0 = sh_hnew[0 * 64 + lane];
    const float h1 = sh_hnew[1 * 64 + lane];
    const float h2 = sh_hnew[2 * 64 + lane];
    const float h3 = sh_hnew[3 * 64 + lane];
#pragma unroll
    for (int q = 0; q < 4; ++q) {
      const int re = rlane_i(reC, q);   // uniform: ro | eo<<8
      const int ro = re & 0xFF;
      const float ha = (ro & 1) ? h1 : h0;
      const float hb = (ro & 1) ? h3 : h2;
      const float hs = (ro & 2) ? hb : ha;
      mtreg[q] = (re & 0x100) ? hs : mtreg[q];
    }
    // no barrier: next A writes only shp (its B1 readers are 2 bars back);
    // sh_hnew is next written in B2(k+1), two barriers away.
  };

  for (int k = 0; k < nT; k += 2) {
    do_step(k, walS0, xpS0, reS0);
    if (k + 1 < nT) do_step(k + 1, walS1, xpS1, reS1);
  }
}

// ---------------------------------------------------------------------------
// memsB: mems[b,t,c,:] = hbuf(tau)[ro(tau,c)*64+:], tau = last step<=t with
// M&Eo, else 0. One block per (b,c).
__global__ __launch_bounds__(512) void memsB(const int* __restrict__ M,
                                             const int* __restrict__ Eo,
                                             const int* __restrict__ Ro,
                                             const float* __restrict__ hbuf,
                                             float* __restrict__ mems) {
  __shared__ int lastA[T_];
  const int tid = threadIdx.x;
  const int b = blockIdx.x >> 6;
  const int c = blockIdx.x & 63;
  const size_t bt0 = (size_t)b * T_;
  {
    const int upd = M[bt0 + tid] & Eo[(bt0 + tid) * C_ + c];
    lastA[tid] = upd ? tid : -1;
  }
  __syncthreads();
  for (int off = 1; off < T_; off <<= 1) {
    const int u = (tid >= off) ? lastA[tid - off] : -1;
    const int v = lastA[tid];
    __syncthreads();
    lastA[tid] = (u > v) ? u : v;
    __syncthreads();
  }
  const int d = tid & 63;
  const int t8 = tid >> 6;
  for (int tt = 0; tt < 64; ++tt) {
    const int t = (tt << 3) + t8;
    const int tau = lastA[t];
    float v = 0.f;
    if (tau >= 0) {
      const int rc = Ro[(bt0 + tau) * C_ + c];
      v = hbuf[(bt0 + tau) * OUT_ + (rc << 6) + d];
    }
    mems[((bt0 + t) * C_ + c) * RD_ + d] = v;
  }
}

// ---------------------------------------------------------------------------
// outsC: outs[b,t,:] = hbuf(tauM), tauM = last M=1 step <= t, else 0.
// In place on hbuf/outs, descending t.
__global__ __launch_bounds__(512) void outsC(const int* __restrict__ M,
                                             float* __restrict__ outs) {
  __shared__ int lastM[T_];
  const int tid = threadIdx.x;
  const int b = blockIdx.x;
  const size_t bt0 = (size_t)b * T_;
  lastM[tid] = M[bt0 + tid] ? tid : -1;
  __syncthreads();
  for (int off = 1; off < T_; off <<= 1) {
    const int u = (tid >= off) ? lastM[tid - off] : -1;
    const int v = lastM[tid];
    __syncthreads();
    lastM[tid] = (u > v) ? u : v;
    __syncthreads();
  }
  const int j = tid & 255;
  const int th = tid >> 8;
  for (int k = 0; k < 256; ++k) {
    const int t = 511 - (k << 1) - th;
    const int tau = lastM[t];
    const float v = (tau >= 0) ? outs[(bt0 + tau) * OUT_ + j] : 0.f;
    __syncthreads();
    outs[(bt0 + t) * OUT_ + j] = v;
  }
}

// ---------------------------------------------------------------------------
extern "C" void kernel_launch(void* const* d_in, const int* in_sizes, int n_in,
                              void* d_out, int out_size, void* d_ws, size_t ws_size,
                              hipStream_t stream) {
  const float* X = (const float*)d_in[0];
  const int* M = (const int*)d_in[1];
  const int* Ei = (const int*)d_in[2];
  const int* Eo = (const int*)d_in[3];
  const int* Ri = (const int*)d_in[4];
  const int* Ro = (const int*)d_in[5];
  const float* W = (const float*)d_in[6];
  const float* U = (const float*)d_in[7];
  const float* Bv = (const float*)d_in[8];
  const float* Watt = (const float*)d_in[9];

  float* outs = (float*)d_out;
  float* mems = outs + (size_t)B_ * T_ * OUT_;
  float* aggs = mems + (size_t)B_ * T_ * C_ * RD_;
  float* XP = (float*)d_ws;   // 16.8 MB scratch
  float* hbuf = outs;         // hnew history aliases outs (outsC finalizes)
  float* walG = mems;         // alpha scratch aliases mems (memsB overwrites)

  xpre_kernel<<<dim3(B_ * T_ / 32), dim3(256), 0, stream>>>(X, W, XP);
  attnK<<<dim3(B_ * T_ / 4), dim3(256), 0, stream>>>(X, Ri, Ei, Watt, walG, aggs);
  gruA<<<dim3(B_), dim3(1024), 0, stream>>>(M, Eo, Ro, U, Bv, XP, walG, hbuf);
  memsB<<<dim3(B_ * C_), dim3(512), 0, stream>>>(M, Eo, Ro, hbuf, mems);
  outsC<<<dim3(B_), dim3(512), 0, stream>>>(M, outs);
}

// Round 15
// 730.007 us; speedup vs baseline: 1.9456x; 1.0519x over previous
//
#include <hip/hip_runtime.h>

#define B_   32
#define T_   512
#define D_   256
#define C_   64
#define R_   4
#define RD_  64
#define OUT_ 256

// ---------------------------------------------------------------------------
__device__ __forceinline__ void bar_lds() {
  asm volatile("s_waitcnt lgkmcnt(0)" ::: "memory");
  __builtin_amdgcn_s_barrier();
  asm volatile("" ::: "memory");
}

// ---- DPP-based wave reductions (VALU pipe) ---------------------------------
template <int CTRL>
__device__ __forceinline__ float dpp_add(float v) {
  int s = __builtin_amdgcn_update_dpp(0, __float_as_int(v), CTRL, 0xF, 0xF, true);
  return v + __int_as_float(s);
}
__device__ __forceinline__ float row16_sum(float v) {
  v = dpp_add<0xB1>(v);   // quad_perm [1,0,3,2]
  v = dpp_add<0x4E>(v);   // quad_perm [2,3,0,1]
  v = dpp_add<0x141>(v);  // row_half_mirror
  v = dpp_add<0x140>(v);  // row_mirror
  return v;
}
__device__ __forceinline__ float rlane(float v, int l) {
  return __int_as_float(__builtin_amdgcn_readlane(__float_as_int(v), l));
}
__device__ __forceinline__ int rlane_i(int v, int l) {
  return __builtin_amdgcn_readlane(v, l);
}
__device__ __forceinline__ float wave_sum_dpp(float v) {
  const float r = row16_sum(v);
  return (rlane(r, 0) + rlane(r, 16)) + (rlane(r, 32) + rlane(r, 48));
}

// ---------------------------------------------------------------------------
// Xpre = X @ W   (16384 x 256) @ (256 x 256), f32
__global__ __launch_bounds__(256) void xpre_kernel(const float* __restrict__ X,
                                                   const float* __restrict__ W,
                                                   float* __restrict__ XP) {
  __shared__ __align__(16) float xs[32][D_];
  const int j = threadIdx.x;
  const int row0 = blockIdx.x * 32;
  for (int k = 0; k < 32; ++k)
    xs[k][j] = X[(size_t)(row0 + k) * D_ + j];
  __syncthreads();
  float acc[32];
#pragma unroll
  for (int k = 0; k < 32; ++k) acc[k] = 0.f;
  for (int d4 = 0; d4 < D_ / 4; ++d4) {
    const float w0 = W[(d4 * 4 + 0) * OUT_ + j];
    const float w1 = W[(d4 * 4 + 1) * OUT_ + j];
    const float w2 = W[(d4 * 4 + 2) * OUT_ + j];
    const float w3 = W[(d4 * 4 + 3) * OUT_ + j];
#pragma unroll
    for (int k = 0; k < 32; ++k) {
      const float4 x4 = *(const float4*)&xs[k][d4 * 4];
      acc[k] = fmaf(x4.x, w0, fmaf(x4.y, w1, fmaf(x4.z, w2, fmaf(x4.w, w3, acc[k]))));
    }
  }
  for (int k = 0; k < 32; ++k)
    XP[(size_t)(row0 + k) * OUT_ + j] = acc[k];
}

// ---------------------------------------------------------------------------
// attnK: attention weights + aggs for ALL (b,t). One wave per (b,t).
// walG[bt*256 + r*64 + c] = (ri[c]==r ? alpha[c] : 0).
__global__ __launch_bounds__(256) void attnK(const float* __restrict__ X,
                                             const int* __restrict__ Ri,
                                             const int* __restrict__ Ei,
                                             const float* __restrict__ Watt,
                                             float* __restrict__ walG,
                                             float* __restrict__ aggs) {
  const int wv = threadIdx.x >> 6;
  const int lane = threadIdx.x & 63;
  const size_t bt = (size_t)blockIdx.x * 4 + wv;
  const int r4 = lane >> 4, seg = lane & 15;

  float y = 0.f;
#pragma unroll
  for (int q = 0; q < 4; ++q) {
    const float4 wt = *(const float4*)&Watt[(r4 << 8) + (seg << 4) + (q << 2)];
    const float4 xv = *(const float4*)&X[bt * D_ + (seg << 4) + (q << 2)];
    y = fmaf(xv.x, wt.x, y);
    y = fmaf(xv.y, wt.y, y);
    y = fmaf(xv.z, wt.z, y);
    y = fmaf(xv.w, wt.w, y);
  }
  y = row16_sum(y);
  const float y0 = rlane(y, 0), y1 = rlane(y, 16);
  const float y2 = rlane(y, 32), y3 = rlane(y, 48);
  const int ric = Ri[bt * C_ + lane];
  const float eic = (float)Ei[bt * C_ + lane];
  float yv = (ric & 1) ? y1 : y0;
  const float yw = (ric & 1) ? y3 : y2;
  yv = (ric & 2) ? yw : yv;
  const float am = __expf(yv) * eic;  // EPS=1e-100 underflows in f32
  const float tot = wave_sum_dpp(am);
  const float alpha = __fdividef(am, tot);

  const float w0 = (ric == 0) ? alpha : 0.f;
  const float w1 = (ric == 1) ? alpha : 0.f;
  const float w2 = (ric == 2) ? alpha : 0.f;
  const float w3 = (ric == 3) ? alpha : 0.f;
  walG[bt * 256 + 0 * C_ + lane] = w0;
  walG[bt * 256 + 1 * C_ + lane] = w1;
  walG[bt * 256 + 2 * C_ + lane] = w2;
  walG[bt * 256 + 3 * C_ + lane] = w3;
  const float s0 = wave_sum_dpp(w0);
  const float s1 = wave_sum_dpp(w1);
  const float s2 = wave_sum_dpp(w2);
  const float s3 = wave_sum_dpp(w3);
  if (lane == 0) {
    float4 v = {s0, s1, s2, s3};
    *(float4*)&aggs[bt * R_] = v;
  }
}

// ---------------------------------------------------------------------------
// gruA: recurrent core. 32 blocks x 1024 threads (16 waves, 4 waves/SIMD).
// Round-14 structure + outsC folded in: gruA now writes the FULL outs tensor
// (step rows in B2; copy-span rows (t_k, t_{k+1}) in C on waves 8-15, where
// sh_hnew is stable — next overwrite is two barriers away; zero-prefix rows
// [0, t_0) in the prologue). memsB still reads the m=1 step rows (untouched).
//  A : wave w owns c in [4w,4w+4): mtreg[4]; 16 RL + 16 FMA -> shp[w][r*64+d]
//  B1: prevX at kidx=16w+(lane&15) (16 bcast reads); h2h over K-range
//      [16w,16w+16): 16 RL : 64 FMA with ureg[64]; shprev stash
//  B2: (waves 0-3) h2h = 16-way pBred sum; gates; hnew; all: reload k+2
//  C : mtreg select-update (4 RL) | outs copy-span (waves 8-15)
__global__ __launch_bounds__(1024, 4) void gruA(
    const int* __restrict__ M, const int* __restrict__ Eo,
    const int* __restrict__ Ro, const float* __restrict__ U,
    const float* __restrict__ Bv, const float* __restrict__ XP,
    const float* __restrict__ walG, float* __restrict__ outs) {
  __shared__ __align__(16) float shp[16][256];    // [wave][r*64+d] prev partials
  __shared__ __align__(16) float pBred[16][256];  // [wave][j] h2h partials
  __shared__ __align__(16) float shprev[OUT_];    // prev[j]
  __shared__ __align__(16) float sh_hnew[OUT_];
  __shared__ int sh_tl[T_];
  __shared__ int sh_nT;

  const int tid = threadIdx.x;
  const int lane = tid & 63;
  const int w = tid >> 6;      // 0..15
  const int b = blockIdx.x;
  const size_t bt0 = (size_t)b * T_;

  // U slice: ureg[jj*16+i] = U[16w+i][jj*64+lane]  (K-range 16 per wave)
  float ureg[64];
#pragma unroll
  for (int jj = 0; jj < 4; ++jj)
#pragma unroll
    for (int i = 0; i < 16; ++i)
      ureg[(jj << 4) + i] = U[(size_t)((w << 4) + i) * OUT_ + (jj << 6) + lane];
  const float breg = Bv[tid & 255];  // used by waves 0-3

  // m state: mtreg[q] = mt[4w+q][lane], init 0
  float mtreg[4];
#pragma unroll
  for (int q = 0; q < 4; ++q) mtreg[q] = 0.f;

  // tlist: indices of m=1 steps (wave 0, ballot prefix scan)
  if (tid < 64) {
    int base = 0;
    for (int ch = 0; ch < 8; ++ch) {
      const int mv = M[bt0 + (ch << 6) + lane];
      const unsigned long long mask = __ballot(mv != 0);
      if (mv) {
        const unsigned long long lt = ((lane == 63) ? ~0ull : ((1ull << (lane + 1)) - 1)) >> 1;
        sh_tl[base + __popcll(mask & lt)] = (ch << 6) + lane;
      }
      base += __popcll(mask);
    }
    if (lane == 0) sh_nT = base;
  }
  __syncthreads();
  const int nT = sh_nT;

  // zero-prefix: outs rows [0, t_0) are h0 = 0 (all rows if nT == 0)
  {
    const int t0 = (nT > 0) ? sh_tl[0] : T_;
    const int j = tid & 255;
    for (int t = tid >> 8; t < t0; t += 4)
      outs[(bt0 + t) * OUT_ + j] = 0.f;
  }
  if (nT == 0) return;

  // parity register sets:
  //  walS : wal[r = lane&3][c = 4w + (lane>>4)]   (A: readlane at (q<<4)+r)
  //  xpS  : XP[., tid]  (waves 0-3 only)
  //  reS  : Ro | (Eo<<8) at c = 4w + (lane&3)     (C: readlane at q)
  const int cwal = (w << 2) + (lane >> 4);
  const int rwal = lane & 3;
  const int croeo = (w << 2) + (lane & 3);
  float walS0 = 0.f, xpS0 = 0.f, walS1 = 0.f, xpS1 = 0.f;
  int reS0 = 0, reS1 = 0;
  {
    const int t0 = sh_tl[0];
    walS0 = walG[(bt0 + t0) * 256 + (rwal << 6) + cwal];
    if (w < 4) xpS0 = XP[(bt0 + t0) * 256 + tid];
    reS0 = Ro[(bt0 + t0) * C_ + croeo] | (Eo[(bt0 + t0) * C_ + croeo] << 8);
  }
  if (nT > 1) {
    const int t1 = sh_tl[1];
    walS1 = walG[(bt0 + t1) * 256 + (rwal << 6) + cwal];
    if (w < 4) xpS1 = XP[(bt0 + t1) * 256 + tid];
    reS1 = Ro[(bt0 + t1) * C_ + croeo] | (Eo[(bt0 + t1) * C_ + croeo] << 8);
  }

  auto do_step = [&](int k, float& walS, float& xpS, int& reS) {
    const int tk = sh_tl[k];
    const size_t bt = bt0 + tk;
    const int reC = reS;  // consume before the k+2 reload overwrites

    // ---- A: prev partials from mtreg (16 RL + 16 FMA) -> shp ----
    float a0 = 0.f, a1 = 0.f, a2 = 0.f, a3 = 0.f;
#pragma unroll
    for (int q = 0; q < 4; ++q) {
      const float mq = mtreg[q];
      a0 = fmaf(rlane(walS, (q << 4) + 0), mq, a0);
      a1 = fmaf(rlane(walS, (q << 4) + 1), mq, a1);
      a2 = fmaf(rlane(walS, (q << 4) + 2), mq, a2);
      a3 = fmaf(rlane(walS, (q << 4) + 3), mq, a3);
    }
    shp[w][0 * 64 + lane] = a0;
    shp[w][1 * 64 + lane] = a1;
    shp[w][2 * 64 + lane] = a2;
    shp[w][3 * 64 + lane] = a3;
    bar_lds();

    // ---- B1: prevX at kidx (16 bcast reads); h2h partials (16 RL:64 FMA) ----
    const int kidx = (w << 4) + (lane & 15);
    float px = 0.f;
#pragma unroll
    for (int sw = 0; sw < 16; sw += 4) {
      const float t0 = shp[sw + 0][kidx], t1 = shp[sw + 1][kidx];
      const float t2 = shp[sw + 2][kidx], t3 = shp[sw + 3][kidx];
      px += (t0 + t1) + (t2 + t3);
    }
    if (lane < 16) shprev[kidx] = px;
    float p0 = 0.f, p1 = 0.f, p2 = 0.f, p3 = 0.f;
#pragma unroll
    for (int i = 0; i < 16; ++i) {
      const float pk = rlane(px, i);  // prev[16w + i], wave-uniform
      p0 = fmaf(pk, ureg[i], p0);
      p1 = fmaf(pk, ureg[16 + i], p1);
      p2 = fmaf(pk, ureg[32 + i], p2);
      p3 = fmaf(pk, ureg[48 + i], p3);
    }
    pBred[w][0 * 64 + lane] = p0;
    pBred[w][1 * 64 + lane] = p1;
    pBred[w][2 * 64 + lane] = p2;
    pBred[w][3 * 64 + lane] = p3;
    bar_lds();

    // ---- B2: gates on waves 0-3; reload parity set for t_{k+2} (all) ----
    if (w < 4) {
      float h2h = 0.f;
#pragma unroll
      for (int kw = 0; kw < 16; kw += 4) {
        const float t0 = pBred[kw + 0][tid], t1 = pBred[kw + 1][tid];
        const float t2 = pBred[kw + 2][tid], t3 = pBred[kw + 3][tid];
        h2h += (t0 + t1) + (t2 + t3);
      }
      const float pOwn = shprev[tid];
      const float g1 = xpS + h2h + breg;
      const float rg = 1.f / (1.f + __expf(-g1));
      const float targ = xpS + rg * h2h + breg;
      const float e2 = __expf(2.f * targ);
      const float ht = 1.f - 2.f / (e2 + 1.f);  // tanh
      const float hn = (1.f - rg) * pOwn + rg * ht;
      sh_hnew[tid] = hn;
      outs[bt * OUT_ + tid] = hn;
    }
    if (k + 2 < nT) {
      const int t2 = sh_tl[k + 2];
      walS = walG[(bt0 + t2) * 256 + (rwal << 6) + cwal];
      if (w < 4) xpS = XP[(bt0 + t2) * 256 + tid];
      reS = Ro[(bt0 + t2) * C_ + croeo] | (Eo[(bt0 + t2) * C_ + croeo] << 8);
    }
    bar_lds();

    // ---- C: mtreg select-update (4 RL; hnew via 4 conflict-free b32) |
    // ----    outs copy-span rows (t_k, t_next) on waves 8-15 --------------
    const float h0 = sh_hnew[0 * 64 + lane];
    const float h1 = sh_hnew[1 * 64 + lane];
    const float h2 = sh_hnew[2 * 64 + lane];
    const float h3 = sh_hnew[3 * 64 + lane];
#pragma unroll
    for (int q = 0; q < 4; ++q) {
      const int re = rlane_i(reC, q);   // uniform: ro | eo<<8
      const int ro = re & 0xFF;
      const float ha = (ro & 1) ? h1 : h0;
      const float hb = (ro & 1) ? h3 : h2;
      const float hs = (ro & 2) ? hb : ha;
      mtreg[q] = (re & 0x100) ? hs : mtreg[q];
    }
    if (w >= 8) {
      // h(t) = hnew(t_k) for t in (t_k, t_next); sh_hnew is stable here
      // (next overwrite is in B2(k+1), two barriers away).
      const int idx = tid - 512;       // 0..511
      const int rr = idx >> 8;         // 0..1
      const int j = idx & 255;
      const int tnext = (k + 1 < nT) ? sh_tl[k + 1] : T_;
      const float hv = sh_hnew[j];
      for (int t = tk + 1 + rr; t < tnext; t += 2)
        outs[(bt0 + t) * OUT_ + j] = hv;
    }
    // no barrier: next A writes only shp (its B1 readers are 2 bars back);
    // sh_hnew is next written in B2(k+1), two barriers away.
  };

  for (int k = 0; k < nT; k += 2) {
    do_step(k, walS0, xpS0, reS0);
    if (k + 1 < nT) do_step(k + 1, walS1, xpS1, reS1);
  }
}

// ---------------------------------------------------------------------------
// memsB: mems[b,t,c,:] = outs-history(tau)[ro(tau,c)*64+:], tau = last step
// <= t with M&Eo, else 0. Rows at M=1 steps hold true hnew (gruA). One block
// per (b,c).
__global__ __launch_bounds__(512) void memsB(const int* __restrict__ M,
                                             const int* __restrict__ Eo,
                                             const int* __restrict__ Ro,
                                             const float* __restrict__ hbuf,
                                             float* __restrict__ mems) {
  __shared__ int lastA[T_];
  const int tid = threadIdx.x;
  const int b = blockIdx.x >> 6;
  const int c = blockIdx.x & 63;
  const size_t bt0 = (size_t)b * T_;
  {
    const int upd = M[bt0 + tid] & Eo[(bt0 + tid) * C_ + c];
    lastA[tid] = upd ? tid : -1;
  }
  __syncthreads();
  for (int off = 1; off < T_; off <<= 1) {
    const int u = (tid >= off) ? lastA[tid - off] : -1;
    const int v = lastA[tid];
    __syncthreads();
    lastA[tid] = (u > v) ? u : v;
    __syncthreads();
  }
  const int d = tid & 63;
  const int t8 = tid >> 6;
  for (int tt = 0; tt < 64; ++tt) {
    const int t = (tt << 3) + t8;
    const int tau = lastA[t];
    float v = 0.f;
    if (tau >= 0) {
      const int rc = Ro[(bt0 + tau) * C_ + c];
      v = hbuf[(bt0 + tau) * OUT_ + (rc << 6) + d];
    }
    mems[((bt0 + t) * C_ + c) * RD_ + d] = v;
  }
}

// ---------------------------------------------------------------------------
extern "C" void kernel_launch(void* const* d_in, const int* in_sizes, int n_in,
                              void* d_out, int out_size, void* d_ws, size_t ws_size,
                              hipStream_t stream) {
  const float* X = (const float*)d_in[0];
  const int* M = (const int*)d_in[1];
  const int* Ei = (const int*)d_in[2];
  const int* Eo = (const int*)d_in[3];
  const int* Ri = (const int*)d_in[4];
  const int* Ro = (const int*)d_in[5];
  const float* W = (const float*)d_in[6];
  const float* U = (const float*)d_in[7];
  const float* Bv = (const float*)d_in[8];
  const float* Watt = (const float*)d_in[9];

  float* outs = (float*)d_out;
  float* mems = outs + (size_t)B_ * T_ * OUT_;
  float* aggs = mems + (size_t)B_ * T_ * C_ * RD_;
  float* XP = (float*)d_ws;   // 16.8 MB scratch
  float* walG = mems;         // alpha scratch aliases mems (memsB overwrites)

  xpre_kernel<<<dim3(B_ * T_ / 32), dim3(256), 0, stream>>>(X, W, XP);
  attnK<<<dim3(B_ * T_ / 4), dim3(256), 0, stream>>>(X, Ri, Ei, Watt, walG, aggs);
  gruA<<<dim3(B_), dim3(1024), 0, stream>>>(M, Eo, Ro, U, Bv, XP, walG, outs);
  memsB<<<dim3(B_ * C_), dim3(512), 0, stream>>>(M, Eo, Ro, outs, mems);
}